// Round 8
// baseline (42.116 us; speedup 1.0000x reference)
//
#include <hip/hip_runtime.h>

#define STEPV (1.0f / 7.0f)
#define L_COORD 5.0f
#define L_NOOBJ 0.5f
#define EPSV 1e-6f

#define TILE 128                               // cells per tile
#define FLOATS_PER_CELL 30
#define TILE_F4 960                            // float4 per tensor per tile
#define NBLK 512                               // persistent blocks = 2 per CU
#define NTHREADS 384                           // 6 waves

typedef const __attribute__((address_space(1))) void cg_void;
typedef __attribute__((address_space(3))) void ls_void;

__global__ __launch_bounds__(NTHREADS) void yolo_loss_kernel(
    const float* __restrict__ pred,
    const float* __restrict__ tgt,
    float* __restrict__ partials,
    int ntiles)
{
    // [dbuf][pred 960 | tgt 960] = 2 * 1920 * 16 B = 61440 B
    __shared__ float4 buf[2][2 * TILE_F4];

    const int tid  = threadIdx.x;
    const int w    = tid >> 6;        // wave 0..5
    const int lane = tid & 63;

    // waves 0-2 stage pred, waves 3-5 stage tgt; 5 x global_load_lds_dwordx4 each.
    // LDS dest: wave-uniform base (HW adds lane*16); global src: per-lane.
    const int wh   = (w < 3) ? w : (w - 3);
    const int toff = (w < 3) ? 0 : TILE_F4;
    const float4* gbase = reinterpret_cast<const float4*>(w < 3 ? pred : tgt);

    #define STAGE(tile_, b_)                                                     \
        do {                                                                     \
            const float4* g_ = gbase + (size_t)(tile_) * TILE_F4 + wh * 320 + lane; \
            float4* l_ = &buf[(b_)][toff + wh * 320];                            \
            _Pragma("unroll")                                                    \
            for (int i_ = 0; i_ < 5; ++i_)                                       \
                __builtin_amdgcn_global_load_lds((cg_void*)(g_ + i_ * 64),       \
                                                 (ls_void*)(l_ + i_ * 64),       \
                                                 16, 0, 0);                      \
        } while (0)

    float loss = 0.0f;
    int it = 0;

    STAGE(blockIdx.x, 0);   // prologue: every block has >=1 tile (NBLK <= ntiles)

    for (int tile = blockIdx.x; tile < ntiles; tile += NBLK, ++it) {
        const int b = it & 1;
        const int nxt = tile + NBLK;

        if (nxt < ntiles) {
            STAGE(nxt, b ^ 1);
            asm volatile("s_waitcnt vmcnt(5)" ::: "memory");  // current tile's 5 loads done
        } else {
            asm volatile("s_waitcnt vmcnt(0)" ::: "memory");
        }
        __builtin_amdgcn_sched_barrier(0);
        __builtin_amdgcn_s_barrier();            // all waves' stage of tile done
        asm volatile("" ::: "memory");

        const float* bufP = reinterpret_cast<const float*>(&buf[b][0]);
        const float* bufT = reinterpret_cast<const float*>(&buf[b][TILE_F4]);

        if (tid < TILE) {
            // ---- waves 0-1: box/conf losses on channels 0..9, one thread per cell
            const int cid  = tid;
            const int cell = tile * TILE + cid;
            const float* p = bufP + cid * FLOATS_PER_CELL;
            const float* t = bufT + cid * FLOATS_PER_CELL;
            float pv[10], tv[10];
            #pragma unroll
            for (int k = 0; k < 5; ++k) {
                float2 a = *reinterpret_cast<const float2*>(p + 2 * k);
                pv[2 * k] = a.x; pv[2 * k + 1] = a.y;
                float2 c = *reinterpret_cast<const float2*>(t + 2 * k);
                tv[2 * k] = c.x; tv[2 * k + 1] = c.y;
            }

            int ij = cell % 49;
            float gy = (float)(ij / 7);
            float gx = (float)(ij % 7);

            float iou[2];
            #pragma unroll
            for (int bb = 0; bb < 2; ++bb) {
                const float* pb = pv + bb * 5;
                const float* tb = tv + bb * 5;
                float x1 = fminf(fmaxf((pb[0] + gx) * STEPV - pb[2] * 0.5f, 0.f), 1.f);
                float y1 = fminf(fmaxf((pb[1] + gy) * STEPV - pb[3] * 0.5f, 0.f), 1.f);
                float w1 = fminf(fmaxf(pb[2], 0.f), 1.f);
                float h1 = fminf(fmaxf(pb[3], 0.f), 1.f);
                float x2 = fminf(fmaxf((tb[0] + gx) * STEPV - tb[2] * 0.5f, 0.f), 1.f);
                float y2 = fminf(fmaxf((tb[1] + gy) * STEPV - tb[3] * 0.5f, 0.f), 1.f);
                float w2 = fminf(fmaxf(tb[2], 0.f), 1.f);
                float h2 = fminf(fmaxf(tb[3], 0.f), 1.f);
                float iw = fmaxf(w1 + w2 - (fmaxf(x1 + w1, x2 + w2) - fminf(x1, x2)), 0.f);
                float ih = fmaxf(h1 + h2 - (fmaxf(y1 + h1, y2 + h2) - fminf(y1, y2)), 0.f);
                float inter = iw * ih;
                float uni = w1 * h1 + w2 * h2 - inter + EPSV;
                iou[bb] = inter / uni;
            }
            int best = (iou[1] > iou[0]) ? 1 : 0;   // argmax tie -> index 0

            float obj_l = 0.f, noobj_l = 0.f, xy_l = 0.f, wh_l = 0.f;
            #pragma unroll
            for (int bb = 0; bb < 2; ++bb) {
                const float* pb = pv + bb * 5;
                const float* tb = tv + bb * 5;
                bool obj = (tb[4] > 0.f) && (bb == best);
                float dc = pb[4] - tb[4];
                dc *= dc;
                if (obj) {
                    obj_l += dc;
                    float dx = pb[0] - tb[0];
                    float dy = pb[1] - tb[1];
                    xy_l += dx * dx + dy * dy;
                    float sw = sqrtf(tb[2] + EPSV) - sqrtf(fmaxf(pb[2], 0.f) + EPSV);
                    float sh = sqrtf(tb[3] + EPSV) - sqrtf(fmaxf(pb[3], 0.f) + EPSV);
                    wh_l += sw * sw + sh * sh;
                } else {
                    noobj_l += dc;
                }
            }
            loss += obj_l + L_NOOBJ * noobj_l + L_COORD * (xy_l + wh_l);
        } else {
            // ---- waves 2-5: class loss, two threads per cell (10 channels each)
            const int q   = tid - TILE;
            const int cid = q >> 1;
            const int sub = q & 1;
            const float* p = bufP + cid * FLOATS_PER_CELL + 10 + sub * 10;
            const float* t = bufT + cid * FLOATS_PER_CELL + 10 + sub * 10;
            float t4 = bufT[cid * FLOATS_PER_CELL + 4];
            float t9 = bufT[cid * FLOATS_PER_CELL + 9];
            bool sig = (t4 > 0.f) || (t9 > 0.f);

            float cls = 0.f;
            #pragma unroll
            for (int k = 0; k < 5; ++k) {
                float2 a = *reinterpret_cast<const float2*>(p + 2 * k);
                float2 c = *reinterpret_cast<const float2*>(t + 2 * k);
                float d0 = a.x - c.x;
                float d1 = a.y - c.y;
                cls += d0 * d0 + d1 * d1;
            }
            if (sig) loss += cls;
        }

        asm volatile("" ::: "memory");
        __builtin_amdgcn_sched_barrier(0);
        __builtin_amdgcn_s_barrier();   // reads of buf[b] done before it is restaged
    }

    // ---- final block reduction (once per block)
    #pragma unroll
    for (int off = 32; off > 0; off >>= 1)
        loss += __shfl_down(loss, off, 64);

    __shared__ float wsum[6];
    if (lane == 0) wsum[w] = loss;
    __syncthreads();
    if (tid == 0) {
        float s = 0.f;
        #pragma unroll
        for (int k = 0; k < 6; ++k) s += wsum[k];
        partials[blockIdx.x] = s;
    }
}

__global__ __launch_bounds__(512) void yolo_finalize(
    const float* __restrict__ partials,
    float* __restrict__ out, int nparts, float invN)
{
    double s = 0.0;
    for (int i = threadIdx.x; i < nparts; i += 512)
        s += (double)partials[i];

    #pragma unroll
    for (int off = 32; off > 0; off >>= 1)
        s += __shfl_down(s, off, 64);

    __shared__ double wsum[8];
    int lane = threadIdx.x & 63;
    int wid  = threadIdx.x >> 6;
    if (lane == 0) wsum[wid] = s;
    __syncthreads();
    if (threadIdx.x == 0) {
        double tot = 0.0;
        #pragma unroll
        for (int k = 0; k < 8; ++k) tot += wsum[k];
        out[0] = (float)(tot * (double)invN);
    }
}

extern "C" void kernel_launch(void* const* d_in, const int* in_sizes, int n_in,
                              void* d_out, int out_size, void* d_ws, size_t ws_size,
                              hipStream_t stream)
{
    const float* pred = (const float*)d_in[0];
    const float* tgt  = (const float*)d_in[1];
    float* out      = (float*)d_out;
    float* partials = (float*)d_ws;    // NBLK floats, all written each call

    int ncells = in_sizes[0] / FLOATS_PER_CELL;   // 802816
    int N = ncells / 49;
    int ntiles = ncells / TILE;                   // 6272, exact

    yolo_loss_kernel<<<NBLK, NTHREADS, 0, stream>>>(pred, tgt, partials, ntiles);
    yolo_finalize<<<1, 512, 0, stream>>>(partials, out, NBLK, 1.0f / (float)N);
}